// Round 1
// baseline (378.993 us; speedup 1.0000x reference)
//
#include <hip/hip_runtime.h>

typedef __attribute__((ext_vector_type(8))) short short8;
typedef __attribute__((ext_vector_type(4))) float f32x4;

__device__ __forceinline__ unsigned short f2bf(float f) {
  union { float f; unsigned u; } v; v.f = f;
  unsigned u = v.u;
  unsigned r = (u + 0x7FFFu + ((u >> 16) & 1u)) >> 16;  // RTNE
  return (unsigned short)r;
}
__device__ __forceinline__ float bf2f(unsigned short s) {
  union { unsigned u; float f; } v; v.u = ((unsigned)s) << 16;
  return v.f;
}

// ---------------- CSR build ----------------

__global__ void zero_int_kernel(int* a, int n, int* b, int nb, int* flag) {
  int i = blockIdx.x * blockDim.x + threadIdx.x;
  int stride = gridDim.x * blockDim.x;
  for (int j = i; j < n; j += stride) a[j] = 0;
  for (int j = i; j < nb; j += stride) b[j] = 0;
  if (i == 0) *flag = 1;
}

// Detect whether edge buffer is int64 (values all in [0,n)) or int32.
__global__ void detect_kernel(const long long* p, int nslots, int n_nodes, int* flag) {
  int i = blockIdx.x * blockDim.x + threadIdx.x;
  if (i < nslots) {
    long long v = p[i];
    if (v < 0 || v >= n_nodes) atomicAnd(flag, 0);
  }
}

__device__ __forceinline__ int edge_at(const void* p, int is64, size_t idx) {
  return is64 ? (int)((const long long*)p)[idx] : ((const int*)p)[idx];
}

__global__ void count_kernel(const void* edges, int E, const int* flag, int* deg) {
  int is64 = *flag;
  int i = blockIdx.x * blockDim.x + threadIdx.x;
  int stride = gridDim.x * blockDim.x;
  for (int e = i; e < E; e += stride) {
    int d = edge_at(edges, is64, (size_t)E + e);
    atomicAdd(&deg[d], 1);
  }
}

__global__ void scan_kernel(const int* __restrict__ deg, int* __restrict__ rs,
                            float* __restrict__ invdeg, int n) {
  __shared__ int s[1024];
  __shared__ int carry;
  int tid = threadIdx.x;
  if (tid == 0) { carry = 0; rs[0] = 0; }
  __syncthreads();
  for (int base = 0; base < n; base += 1024) {
    int i = base + tid;
    int v = (i < n) ? deg[i] : 0;
    s[tid] = v;
    __syncthreads();
    for (int off = 1; off < 1024; off <<= 1) {
      int t = (tid >= off) ? s[tid - off] : 0;
      __syncthreads();
      s[tid] += t;
      __syncthreads();
    }
    if (i < n) {
      rs[i + 1] = carry + s[tid];
      invdeg[i] = 1.0f / fmaxf((float)v, 1.0f);
    }
    __syncthreads();
    if (tid == 0) carry += s[1023];
    __syncthreads();
  }
}

__global__ void fill_kernel(const void* edges, int E, const int* flag,
                            const int* __restrict__ rs, int* cursor, int* col_src) {
  int is64 = *flag;
  int i = blockIdx.x * blockDim.x + threadIdx.x;
  int stride = gridDim.x * blockDim.x;
  for (int e = i; e < E; e += stride) {
    int d = edge_at(edges, is64, (size_t)E + e);
    int s = edge_at(edges, is64, (size_t)e);
    int p = atomicAdd(&cursor[d], 1);
    col_src[rs[d] + p] = s;
  }
}

// ---------------- casts / aggregation ----------------

// x fp32 [n][F] -> bf16 into A at column offset (lda), 4-wide
__global__ void cast_x_kernel(const float* __restrict__ x, unsigned short* __restrict__ A,
                              int total4, int F, int lda, int coloff) {
  int i = blockIdx.x * blockDim.x + threadIdx.x;
  int stride = gridDim.x * blockDim.x;
  for (int idx = i; idx < total4; idx += stride) {
    const float4 v = reinterpret_cast<const float4*>(x)[idx];
    int flat = idx * 4;
    int row = flat / F, f = flat % F;
    ushort4 o;
    o.x = f2bf(v.x); o.y = f2bf(v.y); o.z = f2bf(v.z); o.w = f2bf(v.w);
    *reinterpret_cast<ushort4*>(&A[(size_t)row * lda + coloff + f]) = o;
  }
}

// layer-1 aggregation: gather-sum x (fp32) rows via CSR, write bf16 mean
__global__ void agg_f32_kernel(const float* __restrict__ x, int F,
                               const int* __restrict__ rs, const int* __restrict__ cs,
                               const float* __restrict__ invdeg,
                               unsigned short* __restrict__ out, int ldo) {
  int node = blockIdx.x;
  int f = threadIdx.x;  // blockDim == F
  float acc = 0.f;
  int e1 = rs[node + 1];
  for (int e = rs[node]; e < e1; ++e) {
    int s = cs[e];
    acc += x[(size_t)s * F + f];
  }
  out[(size_t)node * ldo + f] = f2bf(acc * invdeg[node]);
}

// bf16 gather-sum aggregation. blockDim = F/VEC.
template <int VEC>
__global__ void agg_bf16_kernel(const unsigned short* __restrict__ in, int ldi,
                                const int* __restrict__ rs, const int* __restrict__ cs,
                                const float* __restrict__ invdeg,
                                unsigned short* __restrict__ out, int ldo) {
  int node = blockIdx.x;
  int f0 = threadIdx.x * VEC;
  float acc[VEC];
#pragma unroll
  for (int v = 0; v < VEC; ++v) acc[v] = 0.f;
  int e1 = rs[node + 1];
  for (int e = rs[node]; e < e1; ++e) {
    int s = cs[e];
    const unsigned short* p = in + (size_t)s * ldi + f0;
    if (VEC == 4) {
      unsigned long long w = *reinterpret_cast<const unsigned long long*>(p);
      acc[0] += bf2f((unsigned short)w);
      acc[1] += bf2f((unsigned short)(w >> 16));
      acc[2] += bf2f((unsigned short)(w >> 32));
      acc[3] += bf2f((unsigned short)(w >> 48));
    } else {
      unsigned w = *reinterpret_cast<const unsigned*>(p);
      acc[0] += bf2f((unsigned short)w);
      acc[1] += bf2f((unsigned short)(w >> 16));
    }
  }
  float inv = invdeg[node];
  if (VEC == 4) {
    unsigned long long w = (unsigned long long)f2bf(acc[0] * inv)
        | ((unsigned long long)f2bf(acc[1] * inv) << 16)
        | ((unsigned long long)f2bf(acc[2] * inv) << 32)
        | ((unsigned long long)f2bf(acc[3] * inv) << 48);
    *reinterpret_cast<unsigned long long*>(out + (size_t)node * ldo + f0) = w;
  } else {
    unsigned w = (unsigned)f2bf(acc[0] * inv) | ((unsigned)f2bf(acc[1] * inv) << 16);
    *reinterpret_cast<unsigned*>(out + (size_t)node * ldo + f0) = w;
  }
}

// Build Bt [Nout][2F] bf16: Bt[n][k] = k<F ? w_rel[k][n] : w_root[k-F][n]
__global__ void wtrans_kernel(const float* __restrict__ w_rel, const float* __restrict__ w_root,
                              int F, int Nout, unsigned short* __restrict__ Bt) {
  int total = Nout * 2 * F;
  int i = blockIdx.x * blockDim.x + threadIdx.x;
  int stride = gridDim.x * blockDim.x;
  for (int idx = i; idx < total; idx += stride) {
    int n = idx / (2 * F);
    int k = idx % (2 * F);
    float v = (k < F) ? w_rel[(size_t)k * Nout + n] : w_root[(size_t)(k - F) * Nout + n];
    Bt[idx] = f2bf(v);
  }
}

// ---------------- main bf16 MFMA GEMM (128x128 tile, BK=32) ----------------
// C[M][N] = A[M][K] * Bt[N][K]^T + bias, optional relu, bf16 out at col offset.
__launch_bounds__(256, 2)
__global__ void gemm_kernel(const unsigned short* __restrict__ A, int lda,
                            const unsigned short* __restrict__ Bt, int ldb,
                            const float* __restrict__ bias,
                            unsigned short* __restrict__ out, int ldo, int coloff,
                            int M, int N, int K, int relu) {
  __shared__ unsigned short As[128 * 40];
  __shared__ unsigned short Bs[128 * 40];
  int tid = threadIdx.x;
  int lane = tid & 63;
  int w = tid >> 6;
  int wr = w >> 1, wc = w & 1;
  int lr = lane & 15, lk = lane >> 4;
  int m0 = blockIdx.y * 128, n0 = blockIdx.x * 128;

  f32x4 acc[4][4];
#pragma unroll
  for (int i = 0; i < 4; ++i)
#pragma unroll
    for (int j = 0; j < 4; ++j) acc[i][j] = (f32x4)0.0f;

  int arow = tid >> 2;
  int akk = (tid & 3) * 8;

  for (int k0 = 0; k0 < K; k0 += 32) {
#pragma unroll
    for (int it = 0; it < 2; ++it) {
      int row = arow + it * 64;
      int rg = m0 + row;
      uint4 va = make_uint4(0, 0, 0, 0);
      if (rg < M) va = *reinterpret_cast<const uint4*>(A + (size_t)rg * lda + k0 + akk);
      *reinterpret_cast<uint4*>(&As[row * 40 + akk]) = va;
      int ng = n0 + row;
      uint4 vb = make_uint4(0, 0, 0, 0);
      if (ng < N) vb = *reinterpret_cast<const uint4*>(Bt + (size_t)ng * ldb + k0 + akk);
      *reinterpret_cast<uint4*>(&Bs[row * 40 + akk]) = vb;
    }
    __syncthreads();
    short8 af[4], bfr[4];
#pragma unroll
    for (int i = 0; i < 4; ++i) {
      af[i] = *reinterpret_cast<const short8*>(&As[(wr * 64 + i * 16 + lr) * 40 + lk * 8]);
      bfr[i] = *reinterpret_cast<const short8*>(&Bs[(wc * 64 + i * 16 + lr) * 40 + lk * 8]);
    }
#pragma unroll
    for (int i = 0; i < 4; ++i)
#pragma unroll
      for (int j = 0; j < 4; ++j)
        acc[i][j] = __builtin_amdgcn_mfma_f32_16x16x32_bf16(af[i], bfr[j], acc[i][j], 0, 0, 0);
    __syncthreads();
  }

#pragma unroll
  for (int i = 0; i < 4; ++i) {
    int row_b = m0 + wr * 64 + i * 16 + lk * 4;
#pragma unroll
    for (int j = 0; j < 4; ++j) {
      int col = n0 + wc * 64 + j * 16 + lr;
      float bv = bias[col];
#pragma unroll
      for (int r = 0; r < 4; ++r) {
        int row = row_b + r;
        if (row < M) {
          float v = acc[i][j][r] + bv;
          if (relu) v = fmaxf(v, 0.f);
          out[(size_t)row * ldo + coloff + col] = f2bf(v);
        }
      }
    }
  }
}

// ---------------- final N=16 GEMM (mu | logstd), fp32 split output ----------------
__launch_bounds__(256, 2)
__global__ void gemm16_kernel(const unsigned short* __restrict__ A, int lda,
                              const unsigned short* __restrict__ Bt,  // [16][1024]
                              const float* __restrict__ bmu, const float* __restrict__ bls,
                              float* __restrict__ outmu, float* __restrict__ outls,
                              int M, int K) {
  __shared__ unsigned short sB[16 * 1048];
  int tid = threadIdx.x;
  for (int i = tid; i < 16 * 1024 / 4; i += 256) {
    int flat = i * 4;
    int n = flat >> 10, k = flat & 1023;
    ushort4 v = *reinterpret_cast<const ushort4*>(Bt + flat);
    *reinterpret_cast<ushort4*>(&sB[n * 1048 + k]) = v;
  }
  __syncthreads();
  int lane = tid & 63, w = tid >> 6;
  int lr = lane & 15, lk = lane >> 4;
  int rowbase = blockIdx.x * 64 + w * 16;
  f32x4 acc = (f32x4)0.0f;
  int row = rowbase + lr;
  bool rv = row < M;
  const unsigned short* ap = A + (size_t)(rv ? row : 0) * lda + lk * 8;
  for (int k0 = 0; k0 < K; k0 += 32) {
    short8 a = (short8)(short)0;
    if (rv) a = *reinterpret_cast<const short8*>(ap + k0);
    short8 b = *reinterpret_cast<const short8*>(&sB[lr * 1048 + k0 + lk * 8]);
    acc = __builtin_amdgcn_mfma_f32_16x16x32_bf16(a, b, acc, 0, 0, 0);
  }
  int col = lr;
  float bias = (col < 8) ? bmu[col] : bls[col - 8];
#pragma unroll
  for (int r = 0; r < 4; ++r) {
    int ro = rowbase + lk * 4 + r;
    if (ro < M) {
      float v = acc[r] + bias;
      if (col < 8) outmu[(size_t)ro * 8 + col] = v;
      else outls[(size_t)ro * 8 + (col - 8)] = v;
    }
  }
}

// ---------------- host ----------------

extern "C" void kernel_launch(void* const* d_in, const int* in_sizes, int n_in,
                              void* d_out, int out_size, void* d_ws, size_t ws_size,
                              hipStream_t stream) {
  const float* x = (const float*)d_in[0];
  const void* edge = d_in[1];
  const float* w1_rel = (const float*)d_in[2];
  const float* b1 = (const float*)d_in[3];
  const float* w1_root = (const float*)d_in[4];
  const float* w2_rel = (const float*)d_in[5];
  const float* b2 = (const float*)d_in[6];
  const float* w2_root = (const float*)d_in[7];
  const float* wmu_rel = (const float*)d_in[8];
  const float* bmu = (const float*)d_in[9];
  const float* wmu_root = (const float*)d_in[10];
  const float* wls_rel = (const float*)d_in[11];
  const float* bls = (const float*)d_in[12];
  const float* wls_root = (const float*)d_in[13];

  const int FIN = 128, H1 = 1024, H2 = 512;
  const int M = in_sizes[0] / FIN;   // 20000
  const int E = in_sizes[1] / 2;     // 160000
  const int Mpad = ((M + 127) / 128) * 128;

  char* ws = (char*)d_ws;
  size_t off = 0;
  auto alloc = [&](size_t bytes) -> char* {
    char* p = ws + off;
    off = (off + bytes + 255) & ~(size_t)255;
    return p;
  };
  int* flag = (int*)alloc(4);
  int* deg = (int*)alloc((size_t)M * 4);
  int* cursor = (int*)alloc((size_t)M * 4);
  int* rs = (int*)alloc((size_t)(M + 1) * 4);
  float* invdeg = (float*)alloc((size_t)M * 4);
  int* cs = (int*)alloc((size_t)E * 4);
  unsigned short* A1 = (unsigned short*)alloc((size_t)Mpad * 256 * 2);
  unsigned short* A2 = (unsigned short*)alloc((size_t)Mpad * 2048 * 2);
  unsigned short* A3 = (unsigned short*)alloc((size_t)Mpad * 1024 * 2);
  unsigned short* Bt1 = (unsigned short*)alloc((size_t)H1 * 256 * 2);
  unsigned short* Bt2 = (unsigned short*)alloc((size_t)H2 * 2048 * 2);
  unsigned short* Bt3 = (unsigned short*)alloc((size_t)16 * 1024 * 2);

  // CSR build
  zero_int_kernel<<<64, 256, 0, stream>>>(deg, M, cursor, M, flag);
  detect_kernel<<<8, 256, 0, stream>>>((const long long*)edge, 2048, M, flag);
  count_kernel<<<256, 256, 0, stream>>>(edge, E, flag, deg);
  scan_kernel<<<1, 1024, 0, stream>>>(deg, rs, invdeg, M);
  fill_kernel<<<256, 256, 0, stream>>>(edge, E, flag, rs, cursor, cs);

  // Weights (independent of activations)
  wtrans_kernel<<<256, 256, 0, stream>>>(w1_rel, w1_root, FIN, H1, Bt1);
  wtrans_kernel<<<256, 256, 0, stream>>>(w2_rel, w2_root, H1, H2, Bt2);
  wtrans_kernel<<<64, 256, 0, stream>>>(wmu_rel, wmu_root, H2, 8, Bt3);
  wtrans_kernel<<<64, 256, 0, stream>>>(wls_rel, wls_root, H2, 8, Bt3 + 8 * 1024);

  // Layer 1: A1 = [mean(x) | x] bf16, h1 = relu(A1 @ Bt1^T + b1) -> A2[:,1024:]
  cast_x_kernel<<<640, 256, 0, stream>>>(x, A1, M * FIN / 4, FIN, 256, FIN);
  agg_f32_kernel<<<M, 128, 0, stream>>>(x, FIN, rs, cs, invdeg, A1, 256);
  gemm_kernel<<<dim3(H1 / 128, Mpad / 128), 256, 0, stream>>>(
      A1, 256, Bt1, 256, b1, A2, 2048, 1024, M, H1, 256, 1);

  // Layer 2: A2[:,0:1024] = mean(h1); h2 = relu(A2 @ Bt2^T + b2) -> A3[:,512:]
  agg_bf16_kernel<4><<<M, 256, 0, stream>>>(A2 + 1024, 2048, rs, cs, invdeg, A2, 2048);
  gemm_kernel<<<dim3(H2 / 128, Mpad / 128), 256, 0, stream>>>(
      A2, 2048, Bt2, 2048, b2, A3, 1024, 512, M, H2, 2048, 1);

  // Heads: A3[:,0:512] = mean(h2); [mu|ls] = A3 @ Bt3^T + [bmu|bls]
  agg_bf16_kernel<2><<<M, 256, 0, stream>>>(A3 + 512, 1024, rs, cs, invdeg, A3, 1024);
  float* outmu = (float*)d_out;
  float* outls = outmu + (size_t)M * 8;
  gemm16_kernel<<<(M + 63) / 64, 256, 0, stream>>>(A3, 1024, Bt3, bmu, bls, outmu, outls, M, 1024);
}

// Round 2
// 308.306 us; speedup vs baseline: 1.2293x; 1.2293x over previous
//
#include <hip/hip_runtime.h>

typedef __attribute__((ext_vector_type(8))) short short8;
typedef __attribute__((ext_vector_type(4))) float f32x4;
typedef unsigned long long u64;

__device__ __forceinline__ unsigned short f2bf(float f) {
  union { float f; unsigned u; } v; v.f = f;
  unsigned u = v.u;
  unsigned r = (u + 0x7FFFu + ((u >> 16) & 1u)) >> 16;  // RTNE
  return (unsigned short)r;
}
__device__ __forceinline__ float bf2f(unsigned short s) {
  union { unsigned u; float f; } v; v.u = ((unsigned)s) << 16;
  return v.f;
}

// async global->LDS, 16B per lane; LDS dest must be wave-uniform base + lane*16
__device__ __forceinline__ void gl_lds16(const unsigned short* g, unsigned short* l) {
  __builtin_amdgcn_global_load_lds(
      (const __attribute__((address_space(1))) void*)g,
      (__attribute__((address_space(3))) void*)l, 16, 0, 0);
}

// ---------------- CSR build ----------------

__global__ void zero_int_kernel(int* a, int n, int* b, int nb, int* flag) {
  int i = blockIdx.x * blockDim.x + threadIdx.x;
  int stride = gridDim.x * blockDim.x;
  for (int j = i; j < n; j += stride) a[j] = 0;
  for (int j = i; j < nb; j += stride) b[j] = 0;
  if (i == 0) *flag = 1;
}

// Detect whether edge buffer is int64 (values all in [0,n)) or int32.
__global__ void detect_kernel(const long long* p, int nslots, int n_nodes, int* flag) {
  int i = blockIdx.x * blockDim.x + threadIdx.x;
  if (i < nslots) {
    long long v = p[i];
    if (v < 0 || v >= n_nodes) atomicAnd(flag, 0);
  }
}

__device__ __forceinline__ int edge_at(const void* p, int is64, size_t idx) {
  return is64 ? (int)((const long long*)p)[idx] : ((const int*)p)[idx];
}

__global__ void count_kernel(const void* edges, int E, const int* flag, int* deg) {
  int is64 = *flag;
  int i = blockIdx.x * blockDim.x + threadIdx.x;
  int stride = gridDim.x * blockDim.x;
  for (int e = i; e < E; e += stride) {
    int d = edge_at(edges, is64, (size_t)E + e);
    atomicAdd(&deg[d], 1);
  }
}

// single-block chunked scan: thread t owns CHUNK consecutive nodes
__global__ void scan_kernel(const int* __restrict__ deg, int* __restrict__ rs,
                            float* __restrict__ invdeg, int n) {
  __shared__ int ssum[1024];
  int tid = threadIdx.x;
  int chunk = (n + 1023) >> 10;
  int start = tid * chunk;
  int end = min(start + chunk, n);
  int s = 0;
  for (int i = start; i < end; ++i) s += deg[i];
  ssum[tid] = s;
  __syncthreads();
  for (int off = 1; off < 1024; off <<= 1) {
    int t = (tid >= off) ? ssum[tid - off] : 0;
    __syncthreads();
    ssum[tid] += t;
    __syncthreads();
  }
  int run = (tid ? ssum[tid - 1] : 0);
  if (tid == 0) rs[0] = 0;
  for (int i = start; i < end; ++i) {
    int d = deg[i];
    run += d;
    rs[i + 1] = run;
    invdeg[i] = 1.0f / fmaxf((float)d, 1.0f);
  }
}

__global__ void fill_kernel(const void* edges, int E, const int* flag,
                            const int* __restrict__ rs, int* cursor, int* col_src) {
  int is64 = *flag;
  int i = blockIdx.x * blockDim.x + threadIdx.x;
  int stride = gridDim.x * blockDim.x;
  for (int e = i; e < E; e += stride) {
    int d = edge_at(edges, is64, (size_t)E + e);
    int s = edge_at(edges, is64, (size_t)e);
    int p = atomicAdd(&cursor[d], 1);
    col_src[rs[d] + p] = s;
  }
}

// ---------------- casts / aggregation ----------------

// x fp32 [n][F] -> bf16 into A at column offset (lda), 4-wide
__global__ void cast_x_kernel(const float* __restrict__ x, unsigned short* __restrict__ A,
                              int total4, int F, int lda, int coloff) {
  int i = blockIdx.x * blockDim.x + threadIdx.x;
  int stride = gridDim.x * blockDim.x;
  for (int idx = i; idx < total4; idx += stride) {
    const float4 v = reinterpret_cast<const float4*>(x)[idx];
    int flat = idx * 4;
    int row = flat / F, f = flat % F;
    ushort4 o;
    o.x = f2bf(v.x); o.y = f2bf(v.y); o.z = f2bf(v.z); o.w = f2bf(v.w);
    *reinterpret_cast<ushort4*>(&A[(size_t)row * lda + coloff + f]) = o;
  }
}

// layer-1 aggregation: gather-sum x (fp32) rows via CSR, write bf16 mean
__global__ void agg_f32_kernel(const float* __restrict__ x, int F,
                               const int* __restrict__ rs, const int* __restrict__ cs,
                               const float* __restrict__ invdeg,
                               unsigned short* __restrict__ out, int ldo) {
  int node = blockIdx.x;
  int f = threadIdx.x;  // blockDim == F
  float acc = 0.f;
  int e1 = rs[node + 1];
  for (int e = rs[node]; e < e1; ++e) {
    int s = cs[e];
    acc += x[(size_t)s * F + f];
  }
  out[(size_t)node * ldo + f] = f2bf(acc * invdeg[node]);
}

// layer-2 combine: h2[i][c] = relu( inv*sum_j P2[j][c] + P2[i][512+c] + b2[c] )
// P2 [Mpad][1024] bf16 (cols 0-511 rel, 512-1023 root); h2 [Mpad][512] bf16
__global__ void agg2_kernel(const unsigned short* __restrict__ P2,
                            const int* __restrict__ rs, const int* __restrict__ cs,
                            const float* __restrict__ invdeg,
                            const float* __restrict__ b2,
                            unsigned short* __restrict__ h2) {
  int node = blockIdx.x;
  int f0 = threadIdx.x * 4;  // 128 threads * 4 = 512 cols
  float acc0 = 0.f, acc1 = 0.f, acc2 = 0.f, acc3 = 0.f;
  int e1 = rs[node + 1];
  for (int e = rs[node]; e < e1; ++e) {
    int s = cs[e];
    u64 w = *reinterpret_cast<const u64*>(P2 + (size_t)s * 1024 + f0);
    acc0 += bf2f((unsigned short)w);
    acc1 += bf2f((unsigned short)(w >> 16));
    acc2 += bf2f((unsigned short)(w >> 32));
    acc3 += bf2f((unsigned short)(w >> 48));
  }
  float inv = invdeg[node];
  u64 wr = *reinterpret_cast<const u64*>(P2 + (size_t)node * 1024 + 512 + f0);
  float v0 = fmaxf(acc0 * inv + bf2f((unsigned short)wr) + b2[f0 + 0], 0.f);
  float v1 = fmaxf(acc1 * inv + bf2f((unsigned short)(wr >> 16)) + b2[f0 + 1], 0.f);
  float v2 = fmaxf(acc2 * inv + bf2f((unsigned short)(wr >> 32)) + b2[f0 + 2], 0.f);
  float v3 = fmaxf(acc3 * inv + bf2f((unsigned short)(wr >> 48)) + b2[f0 + 3], 0.f);
  u64 o = (u64)f2bf(v0) | ((u64)f2bf(v1) << 16) | ((u64)f2bf(v2) << 32) | ((u64)f2bf(v3) << 48);
  *reinterpret_cast<u64*>(h2 + (size_t)node * 512 + f0) = o;
}

// heads combine: P3 [Mpad][128] f32, cols 0-7 mu_rel, 8-15 mu_root, 16-23 ls_rel, 24-31 ls_root
__global__ void head_agg_kernel(const float* __restrict__ P3,
                                const int* __restrict__ rs, const int* __restrict__ cs,
                                const float* __restrict__ invdeg,
                                const float* __restrict__ bmu, const float* __restrict__ bls,
                                float* __restrict__ outmu, float* __restrict__ outls, int M) {
  int idx = blockIdx.x * blockDim.x + threadIdx.x;
  int node = idx >> 4;
  int c = idx & 15;
  if (node >= M) return;
  int relc = (c < 8) ? c : (16 + (c - 8));
  float acc = 0.f;
  int e1 = rs[node + 1];
  for (int e = rs[node]; e < e1; ++e) acc += P3[(size_t)cs[e] * 128 + relc];
  float v = acc * invdeg[node] + P3[(size_t)node * 128 + relc + 8]
          + ((c < 8) ? bmu[c] : bls[c - 8]);
  if (c < 8) outmu[(size_t)node * 8 + c] = v;
  else outls[(size_t)node * 8 + (c - 8)] = v;
}

// ---------------- weight transposes ----------------

// Bt [Nout][2F]: Bt[n][k] = k<F ? w_rel[k][n] : w_root[k-F][n]   (layer 1)
__global__ void wtrans_kernel(const float* __restrict__ w_rel, const float* __restrict__ w_root,
                              int F, int Nout, unsigned short* __restrict__ Bt) {
  int total = Nout * 2 * F;
  int i = blockIdx.x * blockDim.x + threadIdx.x;
  int stride = gridDim.x * blockDim.x;
  for (int idx = i; idx < total; idx += stride) {
    int n = idx / (2 * F);
    int k = idx % (2 * F);
    float v = (k < F) ? w_rel[(size_t)k * Nout + n] : w_root[(size_t)(k - F) * Nout + n];
    Bt[idx] = f2bf(v);
  }
}

// Bt [2*Half][K]: Bt[n][k] = n<Half ? w_rel[k][n] : w_root[k][n-Half]   (layer 2 cat)
__global__ void wtrans2_kernel(const float* __restrict__ w_rel, const float* __restrict__ w_root,
                               int K, int Half, unsigned short* __restrict__ Bt) {
  int total = 2 * Half * K;
  int i = blockIdx.x * blockDim.x + threadIdx.x;
  int stride = gridDim.x * blockDim.x;
  for (int idx = i; idx < total; idx += stride) {
    int n = idx / K;
    int k = idx % K;
    float v = (n < Half) ? w_rel[(size_t)k * Half + n] : w_root[(size_t)k * Half + (n - Half)];
    Bt[idx] = f2bf(v);
  }
}

// Bt [128][K]: rows 0-7 mu_rel^T, 8-15 mu_root^T, 16-23 ls_rel^T, 24-31 ls_root^T, rest 0
__global__ void wtrans_heads_kernel(const float* __restrict__ wmu_rel, const float* __restrict__ wmu_root,
                                    const float* __restrict__ wls_rel, const float* __restrict__ wls_root,
                                    int K, unsigned short* __restrict__ Bt) {
  int total = 128 * K;
  int i = blockIdx.x * blockDim.x + threadIdx.x;
  int stride = gridDim.x * blockDim.x;
  for (int idx = i; idx < total; idx += stride) {
    int n = idx / K;
    int k = idx % K;
    float v = 0.f;
    if (n < 8) v = wmu_rel[(size_t)k * 8 + n];
    else if (n < 16) v = wmu_root[(size_t)k * 8 + (n - 8)];
    else if (n < 24) v = wls_rel[(size_t)k * 8 + (n - 16)];
    else if (n < 32) v = wls_root[(size_t)k * 8 + (n - 24)];
    Bt[idx] = f2bf(v);
  }
}

// ---------------- bf16 MFMA GEMM, m97 structure ----------------
// C[M][N] = A[M][K] * Bt[N][K]^T (+bias)(relu), 128x128 tile, BK=32,
// global_load_lds width-16 staging into linear LDS. No load predication:
// caller guarantees A has Mpad (mult of 128) valid rows, N%128==0, K%32==0.
__launch_bounds__(256, 2)
__global__ void gemm_kernel(const unsigned short* __restrict__ A, int lda,
                            const unsigned short* __restrict__ Bt, int ldb,
                            const float* __restrict__ bias,
                            void* __restrict__ outp, int ldo,
                            int M, int N, int K, int relu, int out_f32) {
  __shared__ unsigned short As[128 * 32];
  __shared__ unsigned short Bs[128 * 32];
  int tid = threadIdx.x;
  int lane = tid & 63;
  int w = tid >> 6;
  int wr = w >> 1, wc = w & 1;
  int lr = lane & 15, lk = lane >> 4;
  int m0 = blockIdx.y * 128, n0 = blockIdx.x * 128;

  f32x4 acc[4][4];
#pragma unroll
  for (int i = 0; i < 4; ++i)
#pragma unroll
    for (int j = 0; j < 4; ++j) acc[i][j] = (f32x4)0.0f;

  int srow = tid >> 2;          // 0..63
  int scol = (tid & 3) * 8;     // k-offset in shorts
  const unsigned short* ga0 = A + (size_t)(m0 + srow) * lda + scol;
  const unsigned short* ga1 = A + (size_t)(m0 + 64 + srow) * lda + scol;
  const unsigned short* gb0 = Bt + (size_t)(n0 + srow) * ldb + scol;
  const unsigned short* gb1 = Bt + (size_t)(n0 + 64 + srow) * ldb + scol;
  // per-wave LDS dest bases (bytes tid*16 == w*1024 + lane*16)
  unsigned short* la0 = As + w * 512;
  unsigned short* la1 = As + 2048 + w * 512;
  unsigned short* lb0 = Bs + w * 512;
  unsigned short* lb1 = Bs + 2048 + w * 512;

  for (int k0 = 0; k0 < K; k0 += 32) {
    gl_lds16(ga0, la0);
    gl_lds16(ga1, la1);
    gl_lds16(gb0, lb0);
    gl_lds16(gb1, lb1);
    ga0 += 32; ga1 += 32; gb0 += 32; gb1 += 32;
    __syncthreads();
    short8 af[4], bfr[4];
#pragma unroll
    for (int i = 0; i < 4; ++i) {
      af[i]  = *reinterpret_cast<const short8*>(&As[(wr * 64 + i * 16 + lr) * 32 + lk * 8]);
      bfr[i] = *reinterpret_cast<const short8*>(&Bs[(wc * 64 + i * 16 + lr) * 32 + lk * 8]);
    }
#pragma unroll
    for (int i = 0; i < 4; ++i)
#pragma unroll
      for (int j = 0; j < 4; ++j)
        acc[i][j] = __builtin_amdgcn_mfma_f32_16x16x32_bf16(af[i], bfr[j], acc[i][j], 0, 0, 0);
    __syncthreads();
  }

#pragma unroll
  for (int i = 0; i < 4; ++i) {
    int row_b = m0 + wr * 64 + i * 16 + lk * 4;
#pragma unroll
    for (int j = 0; j < 4; ++j) {
      int col = n0 + wc * 64 + j * 16 + lr;
      float bv = bias ? bias[col] : 0.f;
#pragma unroll
      for (int r = 0; r < 4; ++r) {
        int row = row_b + r;
        if (row < M) {
          float v = acc[i][j][r] + bv;
          if (relu) v = fmaxf(v, 0.f);
          if (out_f32) ((float*)outp)[(size_t)row * ldo + col] = v;
          else ((unsigned short*)outp)[(size_t)row * ldo + col] = f2bf(v);
        }
      }
    }
  }
}

// ---------------- host ----------------

extern "C" void kernel_launch(void* const* d_in, const int* in_sizes, int n_in,
                              void* d_out, int out_size, void* d_ws, size_t ws_size,
                              hipStream_t stream) {
  const float* x = (const float*)d_in[0];
  const void* edge = d_in[1];
  const float* w1_rel = (const float*)d_in[2];
  const float* b1 = (const float*)d_in[3];
  const float* w1_root = (const float*)d_in[4];
  const float* w2_rel = (const float*)d_in[5];
  const float* b2 = (const float*)d_in[6];
  const float* w2_root = (const float*)d_in[7];
  const float* wmu_rel = (const float*)d_in[8];
  const float* bmu = (const float*)d_in[9];
  const float* wmu_root = (const float*)d_in[10];
  const float* wls_rel = (const float*)d_in[11];
  const float* bls = (const float*)d_in[12];
  const float* wls_root = (const float*)d_in[13];

  const int FIN = 128, H1 = 1024, H2 = 512;
  const int M = in_sizes[0] / FIN;   // 20000
  const int E = in_sizes[1] / 2;     // 160000
  const int Mpad = ((M + 127) / 128) * 128;

  char* ws = (char*)d_ws;
  size_t off = 0;
  auto alloc = [&](size_t bytes) -> char* {
    char* p = ws + off;
    off = (off + bytes + 255) & ~(size_t)255;
    return p;
  };
  int* flag = (int*)alloc(4);
  int* deg = (int*)alloc((size_t)M * 4);
  int* cursor = (int*)alloc((size_t)M * 4);
  int* rs = (int*)alloc((size_t)(M + 1) * 4);
  float* invdeg = (float*)alloc((size_t)M * 4);
  int* cs = (int*)alloc((size_t)E * 4);
  unsigned short* A1 = (unsigned short*)alloc((size_t)Mpad * 256 * 2);   // [mean(x)|x]
  unsigned short* h1 = (unsigned short*)alloc((size_t)Mpad * 1024 * 2);
  unsigned short* P2 = (unsigned short*)alloc((size_t)Mpad * 1024 * 2);  // [h1@w2_rel | h1@w2_root]
  unsigned short* h2 = (unsigned short*)alloc((size_t)Mpad * 512 * 2);
  float* P3 = (float*)alloc((size_t)Mpad * 128 * 4);                     // heads pre-agg
  unsigned short* Bt1 = (unsigned short*)alloc((size_t)H1 * 256 * 2);
  unsigned short* Bt2 = (unsigned short*)alloc((size_t)1024 * 1024 * 2);
  unsigned short* Bt3 = (unsigned short*)alloc((size_t)128 * 512 * 2);

  // CSR build
  zero_int_kernel<<<64, 256, 0, stream>>>(deg, M, cursor, M, flag);
  detect_kernel<<<8, 256, 0, stream>>>((const long long*)edge, 2048, M, flag);
  count_kernel<<<256, 256, 0, stream>>>(edge, E, flag, deg);
  scan_kernel<<<1, 1024, 0, stream>>>(deg, rs, invdeg, M);
  fill_kernel<<<256, 256, 0, stream>>>(edge, E, flag, rs, cursor, cs);

  // Weights
  wtrans_kernel<<<256, 256, 0, stream>>>(w1_rel, w1_root, FIN, H1, Bt1);
  wtrans2_kernel<<<512, 256, 0, stream>>>(w2_rel, w2_root, H1, H2, Bt2);
  wtrans_heads_kernel<<<64, 256, 0, stream>>>(wmu_rel, wmu_root, wls_rel, wls_root, H2, Bt3);

  // Layer 1: A1 = [mean(x) | x] bf16; h1 = relu(A1 @ Bt1^T + b1)
  cast_x_kernel<<<640, 256, 0, stream>>>(x, A1, M * FIN / 4, FIN, 256, FIN);
  agg_f32_kernel<<<M, 128, 0, stream>>>(x, FIN, rs, cs, invdeg, A1, 256);
  gemm_kernel<<<dim3(H1 / 128, Mpad / 128), 256, 0, stream>>>(
      A1, 256, Bt1, 256, b1, h1, 1024, M, H1, 256, 1, 0);

  // Layer 2 (commuted): P2 = h1 @ [w2_rel | w2_root]; h2 = relu(mean_agg(P2_rel) + P2_root + b2)
  gemm_kernel<<<dim3(1024 / 128, Mpad / 128), 256, 0, stream>>>(
      h1, 1024, Bt2, 1024, nullptr, P2, 1024, M, 1024, 1024, 0, 0);
  agg2_kernel<<<M, 128, 0, stream>>>(P2, rs, cs, invdeg, b2, h2);

  // Heads (commuted): P3 = h2 @ [wmu_rel|wmu_root|wls_rel|wls_root] (fp32 out);
  // mu/ls = mean_agg(P3_rel) + P3_root + bias
  gemm_kernel<<<dim3(1, Mpad / 128), 256, 0, stream>>>(
      h2, 512, Bt3, 512, nullptr, P3, 128, M, 128, 512, 0, 1);
  float* outmu = (float*)d_out;
  float* outls = outmu + (size_t)M * 8;
  head_agg_kernel<<<(M * 16 + 255) / 256, 256, 0, stream>>>(
      P3, rs, cs, invdeg, bmu, bls, outmu, outls, M);
}

// Round 3
// 291.346 us; speedup vs baseline: 1.3008x; 1.0582x over previous
//
#include <hip/hip_runtime.h>

typedef __attribute__((ext_vector_type(8))) short short8;
typedef __attribute__((ext_vector_type(4))) float f32x4;
typedef unsigned long long u64;

__device__ __forceinline__ unsigned short f2bf(float f) {
  union { float f; unsigned u; } v; v.f = f;
  unsigned u = v.u;
  unsigned r = (u + 0x7FFFu + ((u >> 16) & 1u)) >> 16;  // RTNE
  return (unsigned short)r;
}
__device__ __forceinline__ float bf2f(unsigned short s) {
  union { unsigned u; float f; } v; v.u = ((unsigned)s) << 16;
  return v.f;
}

// async global->LDS, 16B per lane; LDS dest must be wave-uniform base + lane*16
__device__ __forceinline__ void gl_lds16(const unsigned short* g, unsigned short* l) {
  __builtin_amdgcn_global_load_lds(
      (const __attribute__((address_space(1))) void*)g,
      (__attribute__((address_space(3))) void*)l, 16, 0, 0);
}

// ---------------- CSR build ----------------

__global__ void zero_int_kernel(int* a, int n, int* b, int nb, int* flag) {
  int i = blockIdx.x * blockDim.x + threadIdx.x;
  int stride = gridDim.x * blockDim.x;
  for (int j = i; j < n; j += stride) a[j] = 0;
  for (int j = i; j < nb; j += stride) b[j] = 0;
  if (i == 0) *flag = 1;
}

// Detect whether edge buffer is int64 (values all in [0,n)) or int32.
__global__ void detect_kernel(const long long* p, int nslots, int n_nodes, int* flag) {
  int i = blockIdx.x * blockDim.x + threadIdx.x;
  if (i < nslots) {
    long long v = p[i];
    if (v < 0 || v >= n_nodes) atomicAnd(flag, 0);
  }
}

__device__ __forceinline__ int edge_at(const void* p, int is64, size_t idx) {
  return is64 ? (int)((const long long*)p)[idx] : ((const int*)p)[idx];
}

__global__ void count_kernel(const void* edges, int E, const int* flag, int* deg) {
  int is64 = *flag;
  int i = blockIdx.x * blockDim.x + threadIdx.x;
  int stride = gridDim.x * blockDim.x;
  for (int e = i; e < E; e += stride) {
    int d = edge_at(edges, is64, (size_t)E + e);
    atomicAdd(&deg[d], 1);
  }
}

// single-block chunked scan: thread t owns CHUNK consecutive nodes
__global__ void scan_kernel(const int* __restrict__ deg, int* __restrict__ rs,
                            float* __restrict__ invdeg, int n) {
  __shared__ int ssum[1024];
  int tid = threadIdx.x;
  int chunk = (n + 1023) >> 10;
  int start = tid * chunk;
  int end = min(start + chunk, n);
  int s = 0;
  for (int i = start; i < end; ++i) s += deg[i];
  ssum[tid] = s;
  __syncthreads();
  for (int off = 1; off < 1024; off <<= 1) {
    int t = (tid >= off) ? ssum[tid - off] : 0;
    __syncthreads();
    ssum[tid] += t;
    __syncthreads();
  }
  int run = (tid ? ssum[tid - 1] : 0);
  if (tid == 0) rs[0] = 0;
  for (int i = start; i < end; ++i) {
    int d = deg[i];
    run += d;
    rs[i + 1] = run;
    invdeg[i] = 1.0f / fmaxf((float)d, 1.0f);
  }
}

__global__ void fill_kernel(const void* edges, int E, const int* flag,
                            const int* __restrict__ rs, int* cursor, int* col_src) {
  int is64 = *flag;
  int i = blockIdx.x * blockDim.x + threadIdx.x;
  int stride = gridDim.x * blockDim.x;
  for (int e = i; e < E; e += stride) {
    int d = edge_at(edges, is64, (size_t)E + e);
    int s = edge_at(edges, is64, (size_t)e);
    int p = atomicAdd(&cursor[d], 1);
    col_src[rs[d] + p] = s;
  }
}

// ---------------- casts / aggregation ----------------

// x fp32 [n][F] -> bf16 into A at column offset (lda), 4-wide
__global__ void cast_x_kernel(const float* __restrict__ x, unsigned short* __restrict__ A,
                              int total4, int F, int lda, int coloff) {
  int i = blockIdx.x * blockDim.x + threadIdx.x;
  int stride = gridDim.x * blockDim.x;
  for (int idx = i; idx < total4; idx += stride) {
    const float4 v = reinterpret_cast<const float4*>(x)[idx];
    int flat = idx * 4;
    int row = flat / F, f = flat % F;
    ushort4 o;
    o.x = f2bf(v.x); o.y = f2bf(v.y); o.z = f2bf(v.z); o.w = f2bf(v.w);
    *reinterpret_cast<ushort4*>(&A[(size_t)row * lda + coloff + f]) = o;
  }
}

// layer-1 aggregation: gather-sum x (fp32) rows via CSR, write bf16 mean
__global__ void agg_f32_kernel(const float* __restrict__ x, int F,
                               const int* __restrict__ rs, const int* __restrict__ cs,
                               const float* __restrict__ invdeg,
                               unsigned short* __restrict__ out, int ldo) {
  int node = blockIdx.x;
  int f = threadIdx.x;  // blockDim == F
  float acc = 0.f;
  int e1 = rs[node + 1];
  for (int e = rs[node]; e < e1; ++e) {
    int s = cs[e];
    acc += x[(size_t)s * F + f];
  }
  out[(size_t)node * ldo + f] = f2bf(acc * invdeg[node]);
}

// layer-2 combine: h2[i][c] = relu( inv*sum_j P2[j][c] + P2[i][512+c] + b2[c] )
// P2 [Mpad][1024] bf16 (cols 0-511 rel, 512-1023 root); h2 [Mpad][512] bf16
__global__ void agg2_kernel(const unsigned short* __restrict__ P2,
                            const int* __restrict__ rs, const int* __restrict__ cs,
                            const float* __restrict__ invdeg,
                            const float* __restrict__ b2,
                            unsigned short* __restrict__ h2) {
  int node = blockIdx.x;
  int f0 = threadIdx.x * 4;  // 128 threads * 4 = 512 cols
  float acc0 = 0.f, acc1 = 0.f, acc2 = 0.f, acc3 = 0.f;
  int e1 = rs[node + 1];
  for (int e = rs[node]; e < e1; ++e) {
    int s = cs[e];
    u64 w = *reinterpret_cast<const u64*>(P2 + (size_t)s * 1024 + f0);
    acc0 += bf2f((unsigned short)w);
    acc1 += bf2f((unsigned short)(w >> 16));
    acc2 += bf2f((unsigned short)(w >> 32));
    acc3 += bf2f((unsigned short)(w >> 48));
  }
  float inv = invdeg[node];
  u64 wr = *reinterpret_cast<const u64*>(P2 + (size_t)node * 1024 + 512 + f0);
  float v0 = fmaxf(acc0 * inv + bf2f((unsigned short)wr) + b2[f0 + 0], 0.f);
  float v1 = fmaxf(acc1 * inv + bf2f((unsigned short)(wr >> 16)) + b2[f0 + 1], 0.f);
  float v2 = fmaxf(acc2 * inv + bf2f((unsigned short)(wr >> 32)) + b2[f0 + 2], 0.f);
  float v3 = fmaxf(acc3 * inv + bf2f((unsigned short)(wr >> 48)) + b2[f0 + 3], 0.f);
  u64 o = (u64)f2bf(v0) | ((u64)f2bf(v1) << 16) | ((u64)f2bf(v2) << 32) | ((u64)f2bf(v3) << 48);
  *reinterpret_cast<u64*>(h2 + (size_t)node * 512 + f0) = o;
}

// heads combine: P3 [Mpad][128] f32, cols 0-7 mu_rel, 8-15 mu_root, 16-23 ls_rel, 24-31 ls_root
__global__ void head_agg_kernel(const float* __restrict__ P3,
                                const int* __restrict__ rs, const int* __restrict__ cs,
                                const float* __restrict__ invdeg,
                                const float* __restrict__ bmu, const float* __restrict__ bls,
                                float* __restrict__ outmu, float* __restrict__ outls, int M) {
  int idx = blockIdx.x * blockDim.x + threadIdx.x;
  int node = idx >> 4;
  int c = idx & 15;
  if (node >= M) return;
  int relc = (c < 8) ? c : (16 + (c - 8));
  float acc = 0.f;
  int e1 = rs[node + 1];
  for (int e = rs[node]; e < e1; ++e) acc += P3[(size_t)cs[e] * 128 + relc];
  float v = acc * invdeg[node] + P3[(size_t)node * 128 + relc + 8]
          + ((c < 8) ? bmu[c] : bls[c - 8]);
  if (c < 8) outmu[(size_t)node * 8 + c] = v;
  else outls[(size_t)node * 8 + (c - 8)] = v;
}

// ---------------- weight transposes ----------------

// Bt [Nout][2F]: Bt[n][k] = k<F ? w_rel[k][n] : w_root[k-F][n]   (layer 1)
__global__ void wtrans_kernel(const float* __restrict__ w_rel, const float* __restrict__ w_root,
                              int F, int Nout, unsigned short* __restrict__ Bt) {
  int total = Nout * 2 * F;
  int i = blockIdx.x * blockDim.x + threadIdx.x;
  int stride = gridDim.x * blockDim.x;
  for (int idx = i; idx < total; idx += stride) {
    int n = idx / (2 * F);
    int k = idx % (2 * F);
    float v = (k < F) ? w_rel[(size_t)k * Nout + n] : w_root[(size_t)(k - F) * Nout + n];
    Bt[idx] = f2bf(v);
  }
}

// Bt [2*Half][K]: Bt[n][k] = n<Half ? w_rel[k][n] : w_root[k][n-Half]   (layer 2 cat)
__global__ void wtrans2_kernel(const float* __restrict__ w_rel, const float* __restrict__ w_root,
                               int K, int Half, unsigned short* __restrict__ Bt) {
  int total = 2 * Half * K;
  int i = blockIdx.x * blockDim.x + threadIdx.x;
  int stride = gridDim.x * blockDim.x;
  for (int idx = i; idx < total; idx += stride) {
    int n = idx / K;
    int k = idx % K;
    float v = (n < Half) ? w_rel[(size_t)k * Half + n] : w_root[(size_t)k * Half + (n - Half)];
    Bt[idx] = f2bf(v);
  }
}

// Bt [128][K]: rows 0-7 mu_rel^T, 8-15 mu_root^T, 16-23 ls_rel^T, 24-31 ls_root^T, rest 0
__global__ void wtrans_heads_kernel(const float* __restrict__ wmu_rel, const float* __restrict__ wmu_root,
                                    const float* __restrict__ wls_rel, const float* __restrict__ wls_root,
                                    int K, unsigned short* __restrict__ Bt) {
  int total = 128 * K;
  int i = blockIdx.x * blockDim.x + threadIdx.x;
  int stride = gridDim.x * blockDim.x;
  for (int idx = i; idx < total; idx += stride) {
    int n = idx / K;
    int k = idx % K;
    float v = 0.f;
    if (n < 8) v = wmu_rel[(size_t)k * 8 + n];
    else if (n < 16) v = wmu_root[(size_t)k * 8 + (n - 8)];
    else if (n < 24) v = wls_rel[(size_t)k * 8 + (n - 16)];
    else if (n < 32) v = wls_root[(size_t)k * 8 + (n - 24)];
    Bt[idx] = f2bf(v);
  }
}

// ---------------- bf16 MFMA GEMM: 128x128 tile, BK=32, 2-phase dbuf, XCD swizzle ----
// C[M][N] = A[M][K] * Bt[N][K]^T (+bias)(relu). 1D grid of gx*gy blocks.
// Caller guarantees Mpad rows valid in A, N%128==0, K%32==0.
__launch_bounds__(256, 3)
__global__ void gemm_kernel(const unsigned short* __restrict__ A, int lda,
                            const unsigned short* __restrict__ Bt, int ldb,
                            const float* __restrict__ bias,
                            void* __restrict__ outp, int ldo,
                            int M, int N, int K, int relu, int out_f32, int gx) {
  __shared__ unsigned short As[2 * 128 * 32];
  __shared__ unsigned short Bs[2 * 128 * 32];
  int tid = threadIdx.x;
  int lane = tid & 63;
  int w = tid >> 6;
  int wr = w >> 1, wc = w & 1;
  int lr = lane & 15, lk = lane >> 4;

  // bijective XCD swizzle (m204): XCD k owns a contiguous chunk of tiles
  int nwg = gridDim.x;
  int orig = blockIdx.x;
  int q = nwg >> 3, r = nwg & 7;
  int xcd = orig & 7, lid = orig >> 3;
  int swz = (xcd < r ? xcd * (q + 1) : r * (q + 1) + (xcd - r) * q) + lid;
  int m0 = (swz / gx) * 128, n0 = (swz % gx) * 128;

  f32x4 acc[4][4];
#pragma unroll
  for (int i = 0; i < 4; ++i)
#pragma unroll
    for (int j = 0; j < 4; ++j) acc[i][j] = (f32x4)0.0f;

  int srow = tid >> 2;          // 0..63
  int scol = (tid & 3) * 8;     // k-offset in shorts
  const unsigned short* gA = A + (size_t)(m0 + srow) * lda + scol;
  const unsigned short* gB = Bt + (size_t)(n0 + srow) * ldb + scol;
  size_t a64 = (size_t)64 * lda, b64 = (size_t)64 * ldb;
  // per-wave LDS dest bases (lane*16B appended by HW)
  unsigned short* lA = As + w * 512;
  unsigned short* lB = Bs + w * 512;

  // prologue: stage tile 0 into buffer 0
  gl_lds16(gA, lA); gl_lds16(gA + a64, lA + 2048);
  gl_lds16(gB, lB); gl_lds16(gB + b64, lB + 2048);
  gA += 32; gB += 32;
  __syncthreads();

  int nt = K >> 5;
  for (int t = 0; t < nt; ++t) {
    int cur = (t & 1) * 4096;
    // stage next tile into the other buffer BEFORE computing current
    if (t + 1 < nt) {
      int nxt = cur ^ 4096;
      gl_lds16(gA, lA + nxt); gl_lds16(gA + a64, lA + nxt + 2048);
      gl_lds16(gB, lB + nxt); gl_lds16(gB + b64, lB + nxt + 2048);
      gA += 32; gB += 32;
    }
    const unsigned short* as_ = As + cur;
    const unsigned short* bs_ = Bs + cur;
    short8 af[4], bfr[4];
#pragma unroll
    for (int i = 0; i < 4; ++i) {
      af[i]  = *reinterpret_cast<const short8*>(&as_[(wr * 64 + i * 16 + lr) * 32 + lk * 8]);
      bfr[i] = *reinterpret_cast<const short8*>(&bs_[(wc * 64 + i * 16 + lr) * 32 + lk * 8]);
    }
#pragma unroll
    for (int i = 0; i < 4; ++i)
#pragma unroll
      for (int j = 0; j < 4; ++j)
        acc[i][j] = __builtin_amdgcn_mfma_f32_16x16x32_bf16(af[i], bfr[j], acc[i][j], 0, 0, 0);
    __syncthreads();  // drains vmcnt(0): next buffer staged; LDS reads done
  }

#pragma unroll
  for (int i = 0; i < 4; ++i) {
    int row_b = m0 + wr * 64 + i * 16 + lk * 4;
#pragma unroll
    for (int j = 0; j < 4; ++j) {
      int col = n0 + wc * 64 + j * 16 + lr;
      float bv = bias ? bias[col] : 0.f;
#pragma unroll
      for (int r = 0; r < 4; ++r) {
        int row = row_b + r;
        if (row < M) {
          float v = acc[i][j][r] + bv;
          if (relu) v = fmaxf(v, 0.f);
          if (out_f32) ((float*)outp)[(size_t)row * ldo + col] = v;
          else ((unsigned short*)outp)[(size_t)row * ldo + col] = f2bf(v);
        }
      }
    }
  }
}

// ---------------- host ----------------

extern "C" void kernel_launch(void* const* d_in, const int* in_sizes, int n_in,
                              void* d_out, int out_size, void* d_ws, size_t ws_size,
                              hipStream_t stream) {
  const float* x = (const float*)d_in[0];
  const void* edge = d_in[1];
  const float* w1_rel = (const float*)d_in[2];
  const float* b1 = (const float*)d_in[3];
  const float* w1_root = (const float*)d_in[4];
  const float* w2_rel = (const float*)d_in[5];
  const float* b2 = (const float*)d_in[6];
  const float* w2_root = (const float*)d_in[7];
  const float* wmu_rel = (const float*)d_in[8];
  const float* bmu = (const float*)d_in[9];
  const float* wmu_root = (const float*)d_in[10];
  const float* wls_rel = (const float*)d_in[11];
  const float* bls = (const float*)d_in[12];
  const float* wls_root = (const float*)d_in[13];

  const int FIN = 128, H1 = 1024, H2 = 512;
  const int M = in_sizes[0] / FIN;   // 20000
  const int E = in_sizes[1] / 2;     // 160000
  const int Mpad = ((M + 127) / 128) * 128;
  const int gy = Mpad / 128;

  char* ws = (char*)d_ws;
  size_t off = 0;
  auto alloc = [&](size_t bytes) -> char* {
    char* p = ws + off;
    off = (off + bytes + 255) & ~(size_t)255;
    return p;
  };
  int* flag = (int*)alloc(4);
  int* deg = (int*)alloc((size_t)M * 4);
  int* cursor = (int*)alloc((size_t)M * 4);
  int* rs = (int*)alloc((size_t)(M + 1) * 4);
  float* invdeg = (float*)alloc((size_t)M * 4);
  int* cs = (int*)alloc((size_t)E * 4);
  unsigned short* A1 = (unsigned short*)alloc((size_t)Mpad * 256 * 2);   // [mean(x)|x]
  unsigned short* h1 = (unsigned short*)alloc((size_t)Mpad * 1024 * 2);
  unsigned short* P2 = (unsigned short*)alloc((size_t)Mpad * 1024 * 2);  // [h1@w2_rel | h1@w2_root]
  unsigned short* h2 = (unsigned short*)alloc((size_t)Mpad * 512 * 2);
  float* P3 = (float*)alloc((size_t)Mpad * 128 * 4);                     // heads pre-agg
  unsigned short* Bt1 = (unsigned short*)alloc((size_t)H1 * 256 * 2);
  unsigned short* Bt2 = (unsigned short*)alloc((size_t)1024 * 1024 * 2);
  unsigned short* Bt3 = (unsigned short*)alloc((size_t)128 * 512 * 2);

  // CSR build
  zero_int_kernel<<<64, 256, 0, stream>>>(deg, M, cursor, M, flag);
  detect_kernel<<<8, 256, 0, stream>>>((const long long*)edge, 2048, M, flag);
  count_kernel<<<256, 256, 0, stream>>>(edge, E, flag, deg);
  scan_kernel<<<1, 1024, 0, stream>>>(deg, rs, invdeg, M);
  fill_kernel<<<256, 256, 0, stream>>>(edge, E, flag, rs, cursor, cs);

  // Weights
  wtrans_kernel<<<256, 256, 0, stream>>>(w1_rel, w1_root, FIN, H1, Bt1);
  wtrans2_kernel<<<512, 256, 0, stream>>>(w2_rel, w2_root, H1, H2, Bt2);
  wtrans_heads_kernel<<<64, 256, 0, stream>>>(wmu_rel, wmu_root, wls_rel, wls_root, H2, Bt3);

  // Layer 1: A1 = [mean(x) | x] bf16; h1 = relu(A1 @ Bt1^T + b1)
  cast_x_kernel<<<640, 256, 0, stream>>>(x, A1, M * FIN / 4, FIN, 256, FIN);
  agg_f32_kernel<<<M, 128, 0, stream>>>(x, FIN, rs, cs, invdeg, A1, 256);
  gemm_kernel<<<(H1 / 128) * gy, 256, 0, stream>>>(
      A1, 256, Bt1, 256, b1, h1, 1024, M, H1, 256, 1, 0, H1 / 128);

  // Layer 2 (commuted): P2 = h1 @ [w2_rel | w2_root]; h2 = relu(mean_agg(P2_rel) + P2_root + b2)
  gemm_kernel<<<(1024 / 128) * gy, 256, 0, stream>>>(
      h1, 1024, Bt2, 1024, nullptr, P2, 1024, M, 1024, 1024, 0, 0, 1024 / 128);
  agg2_kernel<<<M, 128, 0, stream>>>(P2, rs, cs, invdeg, b2, h2);

  // Heads (commuted): P3 = h2 @ [wmu_rel|wmu_root|wls_rel|wls_root] (fp32 out);
  // mu/ls = mean_agg(P3_rel) + P3_root + bias
  gemm_kernel<<<1 * gy, 256, 0, stream>>>(
      h2, 512, Bt3, 512, nullptr, P3, 128, M, 128, 512, 0, 1, 1);
  float* outmu = (float*)d_out;
  float* outls = outmu + (size_t)M * 8;
  head_agg_kernel<<<(M * 16 + 255) / 256, 256, 0, stream>>>(
      P3, rs, cs, invdeg, bmu, bls, outmu, outls, M);
}

// Round 4
// 278.005 us; speedup vs baseline: 1.3633x; 1.0480x over previous
//
#include <hip/hip_runtime.h>

typedef __attribute__((ext_vector_type(8))) short short8;
typedef __attribute__((ext_vector_type(4))) float f32x4;
typedef unsigned long long u64;

__device__ __forceinline__ unsigned short f2bf(float f) {
  union { float f; unsigned u; } v; v.f = f;
  unsigned u = v.u;
  unsigned r = (u + 0x7FFFu + ((u >> 16) & 1u)) >> 16;  // RTNE
  return (unsigned short)r;
}
__device__ __forceinline__ float bf2f(unsigned short s) {
  union { unsigned u; float f; } v; v.u = ((unsigned)s) << 16;
  return v.f;
}

// async global->LDS, 16B per lane; LDS dest = wave-uniform base + lane*16
__device__ __forceinline__ void gl_lds16(const unsigned short* g, unsigned short* l) {
  __builtin_amdgcn_global_load_lds(
      (const __attribute__((address_space(1))) void*)g,
      (__attribute__((address_space(3))) void*)l, 16, 0, 0);
}

// ---------------- CSR build ----------------

__global__ void init_kernel(int* a, int n, int* b, int nb, int* flag,
                            const long long* edges, int nslots, int n_nodes) {
  int i = blockIdx.x * blockDim.x + threadIdx.x;
  int stride = gridDim.x * blockDim.x;
  for (int j = i; j < n; j += stride) a[j] = 0;
  for (int j = i; j < nb; j += stride) b[j] = 0;
  if (i == 0) *flag = 1;
  // detect int64 vs int32 edge buffer: int64 values must all lie in [0, n_nodes)
  for (int j = i; j < nslots; j += stride) {
    long long v = edges[j];
    if (v < 0 || v >= n_nodes) atomicAnd(flag, 0);
  }
}

__device__ __forceinline__ int edge_at(const void* p, int is64, size_t idx) {
  return is64 ? (int)((const long long*)p)[idx] : ((const int*)p)[idx];
}

__global__ void count_kernel(const void* edges, int E, const int* flag, int* deg) {
  int is64 = *flag;
  int i = blockIdx.x * blockDim.x + threadIdx.x;
  int stride = gridDim.x * blockDim.x;
  for (int e = i; e < E; e += stride) {
    int d = edge_at(edges, is64, (size_t)E + e);
    atomicAdd(&deg[d], 1);
  }
}

// single-block chunked scan
__global__ void scan_kernel(const int* __restrict__ deg, int* __restrict__ rs,
                            float* __restrict__ invdeg, int n) {
  __shared__ int ssum[1024];
  int tid = threadIdx.x;
  int chunk = (n + 1023) >> 10;
  int start = tid * chunk;
  int end = min(start + chunk, n);
  int s = 0;
  for (int i = start; i < end; ++i) s += deg[i];
  ssum[tid] = s;
  __syncthreads();
  for (int off = 1; off < 1024; off <<= 1) {
    int t = (tid >= off) ? ssum[tid - off] : 0;
    __syncthreads();
    ssum[tid] += t;
    __syncthreads();
  }
  int run = (tid ? ssum[tid - 1] : 0);
  if (tid == 0) rs[0] = 0;
  for (int i = start; i < end; ++i) {
    int d = deg[i];
    run += d;
    rs[i + 1] = run;
    invdeg[i] = 1.0f / fmaxf((float)d, 1.0f);
  }
}

__global__ void fill_kernel(const void* edges, int E, const int* flag,
                            const int* __restrict__ rs, int* cursor, int* col_src) {
  int is64 = *flag;
  int i = blockIdx.x * blockDim.x + threadIdx.x;
  int stride = gridDim.x * blockDim.x;
  for (int e = i; e < E; e += stride) {
    int d = edge_at(edges, is64, (size_t)E + e);
    int s = edge_at(edges, is64, (size_t)e);
    int p = atomicAdd(&cursor[d], 1);
    col_src[rs[d] + p] = s;
  }
}

// ---------------- aggregation ----------------

// layer-1: A1[node] = [ bf16(mean_j x_j) | bf16(x_node) ]   (fused cast+agg)
__global__ void agg1_kernel(const float* __restrict__ x,
                            const int* __restrict__ rs, const int* __restrict__ cs,
                            const float* __restrict__ invdeg,
                            unsigned short* __restrict__ A1) {
  int node = blockIdx.x;
  int f = threadIdx.x;  // 128
  float xi = x[(size_t)node * 128 + f];
  float acc = 0.f;
  int e1 = rs[node + 1];
  for (int e = rs[node]; e < e1; ++e) {
    acc += x[(size_t)cs[e] * 128 + f];
  }
  A1[(size_t)node * 256 + f] = f2bf(acc * invdeg[node]);
  A1[(size_t)node * 256 + 128 + f] = f2bf(xi);
}

// layer-2 combine: h2[i][c] = relu( inv*sum_j P2[j][c] + P2[i][512+c] + b2[c] )
__global__ void agg2_kernel(const unsigned short* __restrict__ P2,
                            const int* __restrict__ rs, const int* __restrict__ cs,
                            const float* __restrict__ invdeg,
                            const float* __restrict__ b2,
                            unsigned short* __restrict__ h2) {
  int node = blockIdx.x;
  int f0 = threadIdx.x * 4;  // 128 threads * 4 = 512 cols
  float acc0 = 0.f, acc1 = 0.f, acc2 = 0.f, acc3 = 0.f;
  int e1 = rs[node + 1];
  for (int e = rs[node]; e < e1; ++e) {
    int s = cs[e];
    u64 w = *reinterpret_cast<const u64*>(P2 + (size_t)s * 1024 + f0);
    acc0 += bf2f((unsigned short)w);
    acc1 += bf2f((unsigned short)(w >> 16));
    acc2 += bf2f((unsigned short)(w >> 32));
    acc3 += bf2f((unsigned short)(w >> 48));
  }
  float inv = invdeg[node];
  u64 wr = *reinterpret_cast<const u64*>(P2 + (size_t)node * 1024 + 512 + f0);
  float v0 = fmaxf(acc0 * inv + bf2f((unsigned short)wr) + b2[f0 + 0], 0.f);
  float v1 = fmaxf(acc1 * inv + bf2f((unsigned short)(wr >> 16)) + b2[f0 + 1], 0.f);
  float v2 = fmaxf(acc2 * inv + bf2f((unsigned short)(wr >> 32)) + b2[f0 + 2], 0.f);
  float v3 = fmaxf(acc3 * inv + bf2f((unsigned short)(wr >> 48)) + b2[f0 + 3], 0.f);
  u64 o = (u64)f2bf(v0) | ((u64)f2bf(v1) << 16) | ((u64)f2bf(v2) << 32) | ((u64)f2bf(v3) << 48);
  *reinterpret_cast<u64*>(h2 + (size_t)node * 512 + f0) = o;
}

// heads combine: P3 [Mpad][128] f32, cols 0-7 mu_rel, 8-15 mu_root, 16-23 ls_rel, 24-31 ls_root
__global__ void head_agg_kernel(const float* __restrict__ P3,
                                const int* __restrict__ rs, const int* __restrict__ cs,
                                const float* __restrict__ invdeg,
                                const float* __restrict__ bmu, const float* __restrict__ bls,
                                float* __restrict__ outmu, float* __restrict__ outls, int M) {
  int idx = blockIdx.x * blockDim.x + threadIdx.x;
  int node = idx >> 4;
  int c = idx & 15;
  if (node >= M) return;
  int relc = (c < 8) ? c : (16 + (c - 8));
  float acc = 0.f;
  int e1 = rs[node + 1];
  for (int e = rs[node]; e < e1; ++e) acc += P3[(size_t)cs[e] * 128 + relc];
  float v = acc * invdeg[node] + P3[(size_t)node * 128 + relc + 8]
          + ((c < 8) ? bmu[c] : bls[c - 8]);
  if (c < 8) outmu[(size_t)node * 8 + c] = v;
  else outls[(size_t)node * 8 + (c - 8)] = v;
}

// ---------------- weight transposes (LDS-tiled, coalesced) ----------------

// transpose one 32x32 tile: dst[(rowoff+n)*ldd + coloff + k] = src[k*Nw + n]
__device__ __forceinline__ void ttile(const float* __restrict__ src, int Nw,
                                      unsigned short* __restrict__ dst, int ldd,
                                      int rowoff, int coloff,
                                      int tileIdx, int tilesN, float (*tile)[33]) {
  int tk = tileIdx / tilesN, tn = tileIdx % tilesN;
  int k0 = tk * 32, n0 = tn * 32;
  int tx = threadIdx.x & 31, ty = threadIdx.x >> 5;  // 256 thr: ty 0..7
#pragma unroll
  for (int s = 0; s < 4; ++s)
    tile[ty + s * 8][tx] = src[(size_t)(k0 + ty + s * 8) * Nw + n0 + tx];
  __syncthreads();
#pragma unroll
  for (int s = 0; s < 4; ++s)
    dst[(size_t)(rowoff + n0 + ty + s * 8) * ldd + coloff + k0 + tx] =
        f2bf(tile[tx][ty + s * 8]);
}

// Bt1 [1024][256] = [w1_rel^T | w1_root^T]; Bt2 [1024][1024] = [w2_rel^T ; w2_root^T];
// Bt3 [32+][512] = 4 head mats^T stacked
__global__ void wtrans_all_kernel(const float* __restrict__ w1_rel, const float* __restrict__ w1_root,
                                  const float* __restrict__ w2_rel, const float* __restrict__ w2_root,
                                  const float* __restrict__ wmu_rel, const float* __restrict__ wmu_root,
                                  const float* __restrict__ wls_rel, const float* __restrict__ wls_root,
                                  unsigned short* __restrict__ Bt1,
                                  unsigned short* __restrict__ Bt2,
                                  unsigned short* __restrict__ Bt3) {
  __shared__ float tile[32][33];
  int b = blockIdx.x;
  if (b < 128)       ttile(w1_rel, 1024, Bt1, 256, 0, 0, b, 32, tile);          // [128][1024]
  else if (b < 256)  ttile(w1_root, 1024, Bt1, 256, 0, 128, b - 128, 32, tile); // [128][1024]
  else if (b < 768)  ttile(w2_rel, 512, Bt2, 1024, 0, 0, b - 256, 16, tile);    // [1024][512]
  else if (b < 1280) ttile(w2_root, 512, Bt2, 1024, 512, 0, b - 768, 16, tile); // [1024][512]
  else {
    int idx = (b - 1280) * 256 + threadIdx.x;  // 64 blocks * 256 = 16384 = 32*512
    int n = idx >> 9, k = idx & 511;
    float v;
    if (n < 8) v = wmu_rel[(size_t)k * 8 + n];
    else if (n < 16) v = wmu_root[(size_t)k * 8 + (n - 8)];
    else if (n < 24) v = wls_rel[(size_t)k * 8 + (n - 16)];
    else v = wls_root[(size_t)k * 8 + (n - 24)];
    Bt3[(size_t)n * 512 + k] = f2bf(v);
  }
}

// ---------------- bf16 MFMA GEMM ----------------
// 128x128 tile, BK=32, 3-deep LDS ring, counted vmcnt, XOR-swizzled LDS,
// XCD-swizzled 1D grid. C = A[M][K] * Bt[N][K]^T (+bias)(relu).
// Caller guarantees Mpad rows valid/readable, N%128==0, K%32==0, K>=64.
__launch_bounds__(256, 3)
__global__ void gemm_kernel(const unsigned short* __restrict__ A, int lda,
                            const unsigned short* __restrict__ Bt, int ldb,
                            const float* __restrict__ bias,
                            void* __restrict__ outp, int ldo,
                            int M, int N, int K, int relu, int out_f32, int gx) {
  __shared__ unsigned short As[3 * 4096];  // 3 ring slots of [128 rows][32 shorts]
  __shared__ unsigned short Bs[3 * 4096];
  int tid = threadIdx.x;
  int lane = tid & 63;
  int w = tid >> 6;
  int wr = w >> 1, wc = w & 1;
  int lr = lane & 15, lk = lane >> 4;

  // bijective XCD swizzle (m204)
  int nwg = gridDim.x, orig = blockIdx.x;
  int q = nwg >> 3, r = nwg & 7;
  int xcd = orig & 7, lid = orig >> 3;
  int swz = (xcd < r ? xcd * (q + 1) : r * (q + 1) + (xcd - r) * q) + lid;
  int m0 = (swz / gx) * 128, n0 = (swz % gx) * 128;

  f32x4 acc[4][4];
#pragma unroll
  for (int i = 0; i < 4; ++i)
#pragma unroll
    for (int j = 0; j < 4; ++j) acc[i][j] = (f32x4)0.0f;

  // staging: thread covers rows r0 and r0+64, physical 16B-slot (tid&3).
  // LDS phys slot = logical slot ^ ((row>>1)&3)  => fetch logical slot
  // slog = (tid&3) ^ ((r0>>1)&3) from global. (r0+64 gives same xor term.)
  int r0 = tid >> 2;
  int slog = (tid & 3) ^ ((r0 >> 1) & 3);
  const unsigned short* gA = A + (size_t)(m0 + r0) * lda + slog * 8;
  const unsigned short* gB = Bt + (size_t)(n0 + r0) * ldb + slog * 8;
  size_t a64 = (size_t)64 * lda, b64 = (size_t)64 * ldb;
  unsigned short* wa = As + w * 512;  // per-wave region (1024 B)
  unsigned short* wb = Bs + w * 512;

  // swizzled read slot, constant per lane (fragment row base is mult of 16)
  int sw8 = (lk ^ ((lr >> 1) & 3)) * 8;

  int nt = K >> 5;  // assumed >= 2
  // prologue: stage tiles 0,1 into ring slots 0,1 (4 loads each per thread)
  gl_lds16(gA, wa); gl_lds16(gA + a64, wa + 2048);
  gl_lds16(gB, wb); gl_lds16(gB + b64, wb + 2048);
  gA += 32; gB += 32;
  gl_lds16(gA, wa + 4096); gl_lds16(gA + a64, wa + 6144);
  gl_lds16(gB, wb + 4096); gl_lds16(gB + b64, wb + 6144);
  gA += 32; gB += 32;
  asm volatile("s_waitcnt vmcnt(4)" ::: "memory");  // tile 0 landed; tile 1 in flight
  __builtin_amdgcn_s_barrier();

  int bufR = 0, bufS = 2;
  for (int t = 0; t < nt; ++t) {
    if (t + 2 < nt) {  // stage tile t+2 into slot bufS (read 2 iters ago -> free)
      unsigned short* sa = As + bufS * 4096 + w * 512;
      unsigned short* sb = Bs + bufS * 4096 + w * 512;
      gl_lds16(gA, sa); gl_lds16(gA + a64, sa + 2048);
      gl_lds16(gB, sb); gl_lds16(gB + b64, sb + 2048);
      gA += 32; gB += 32;
    }
    const unsigned short* as_ = As + bufR * 4096;
    const unsigned short* bs_ = Bs + bufR * 4096;
    short8 af[4], bfr[4];
#pragma unroll
    for (int i = 0; i < 4; ++i) {
      af[i]  = *reinterpret_cast<const short8*>(&as_[(wr * 64 + i * 16 + lr) * 32 + sw8]);
      bfr[i] = *reinterpret_cast<const short8*>(&bs_[(wc * 64 + i * 16 + lr) * 32 + sw8]);
    }
    __builtin_amdgcn_s_setprio(1);
#pragma unroll
    for (int i = 0; i < 4; ++i)
#pragma unroll
      for (int j = 0; j < 4; ++j)
        acc[i][j] = __builtin_amdgcn_mfma_f32_16x16x32_bf16(af[i], bfr[j], acc[i][j], 0, 0, 0);
    __builtin_amdgcn_s_setprio(0);
    if (t + 1 < nt) {
      if (t + 2 < nt)
        asm volatile("s_waitcnt vmcnt(4) lgkmcnt(0)" ::: "memory");  // tile t+1 landed; t+2 in flight
      else
        asm volatile("s_waitcnt vmcnt(0) lgkmcnt(0)" ::: "memory");  // drain tail
      __builtin_amdgcn_s_barrier();
    }
    bufR = (bufR == 2) ? 0 : bufR + 1;
    bufS = (bufS == 2) ? 0 : bufS + 1;
  }

#pragma unroll
  for (int i = 0; i < 4; ++i) {
    int row_b = m0 + wr * 64 + i * 16 + lk * 4;
#pragma unroll
    for (int j = 0; j < 4; ++j) {
      int col = n0 + wc * 64 + j * 16 + lr;
      float bv = bias ? bias[col] : 0.f;
#pragma unroll
      for (int rr = 0; rr < 4; ++rr) {
        int row = row_b + rr;
        if (row < M) {
          float v = acc[i][j][rr] + bv;
          if (relu) v = fmaxf(v, 0.f);
          if (out_f32) ((float*)outp)[(size_t)row * ldo + col] = v;
          else ((unsigned short*)outp)[(size_t)row * ldo + col] = f2bf(v);
        }
      }
    }
  }
}

// ---------------- host ----------------

extern "C" void kernel_launch(void* const* d_in, const int* in_sizes, int n_in,
                              void* d_out, int out_size, void* d_ws, size_t ws_size,
                              hipStream_t stream) {
  const float* x = (const float*)d_in[0];
  const void* edge = d_in[1];
  const float* w1_rel = (const float*)d_in[2];
  const float* b1 = (const float*)d_in[3];
  const float* w1_root = (const float*)d_in[4];
  const float* w2_rel = (const float*)d_in[5];
  const float* b2 = (const float*)d_in[6];
  const float* w2_root = (const float*)d_in[7];
  const float* wmu_rel = (const float*)d_in[8];
  const float* bmu = (const float*)d_in[9];
  const float* wmu_root = (const float*)d_in[10];
  const float* wls_rel = (const float*)d_in[11];
  const float* bls = (const float*)d_in[12];
  const float* wls_root = (const float*)d_in[13];

  const int FIN = 128, H1 = 1024, H2 = 512;
  const int M = in_sizes[0] / FIN;   // 20000
  const int E = in_sizes[1] / 2;     // 160000
  const int Mpad = ((M + 127) / 128) * 128;
  const int gy = Mpad / 128;

  char* ws = (char*)d_ws;
  size_t off = 0;
  auto alloc = [&](size_t bytes) -> char* {
    char* p = ws + off;
    off = (off + bytes + 255) & ~(size_t)255;
    return p;
  };
  int* flag = (int*)alloc(4);
  int* deg = (int*)alloc((size_t)M * 4);
  int* cursor = (int*)alloc((size_t)M * 4);
  int* rs = (int*)alloc((size_t)(M + 1) * 4);
  float* invdeg = (float*)alloc((size_t)M * 4);
  int* cs = (int*)alloc((size_t)E * 4);
  unsigned short* A1 = (unsigned short*)alloc((size_t)Mpad * 256 * 2);   // [mean(x)|x]
  unsigned short* h1 = (unsigned short*)alloc((size_t)Mpad * 1024 * 2);
  unsigned short* P2 = (unsigned short*)alloc((size_t)Mpad * 1024 * 2);  // [h1@w2_rel | h1@w2_root]
  unsigned short* h2 = (unsigned short*)alloc((size_t)Mpad * 512 * 2);
  float* P3 = (float*)alloc((size_t)Mpad * 128 * 4);                     // heads pre-agg
  unsigned short* Bt1 = (unsigned short*)alloc((size_t)H1 * 256 * 2);
  unsigned short* Bt2 = (unsigned short*)alloc((size_t)1024 * 1024 * 2);
  unsigned short* Bt3 = (unsigned short*)alloc((size_t)128 * 512 * 2);

  // CSR build
  init_kernel<<<64, 256, 0, stream>>>(deg, M, cursor, M, flag, (const long long*)edge, 2048, M);
  count_kernel<<<256, 256, 0, stream>>>(edge, E, flag, deg);
  scan_kernel<<<1, 1024, 0, stream>>>(deg, rs, invdeg, M);
  fill_kernel<<<256, 256, 0, stream>>>(edge, E, flag, rs, cursor, cs);

  // Weights (coalesced tiled transpose, one launch)
  wtrans_all_kernel<<<1344, 256, 0, stream>>>(w1_rel, w1_root, w2_rel, w2_root,
                                              wmu_rel, wmu_root, wls_rel, wls_root,
                                              Bt1, Bt2, Bt3);

  // Layer 1: A1 = [mean(x) | x] bf16; h1 = relu(A1 @ Bt1^T + b1)
  agg1_kernel<<<M, 128, 0, stream>>>(x, rs, cs, invdeg, A1);
  gemm_kernel<<<(H1 / 128) * gy, 256, 0, stream>>>(
      A1, 256, Bt1, 256, b1, h1, 1024, M, H1, 256, 1, 0, H1 / 128);

  // Layer 2 (commuted): P2 = h1 @ [w2_rel | w2_root]; h2 = relu(mean_agg(P2_rel) + P2_root + b2)
  gemm_kernel<<<(1024 / 128) * gy, 256, 0, stream>>>(
      h1, 1024, Bt2, 1024, nullptr, P2, 1024, M, 1024, 1024, 0, 0, 1024 / 128);
  agg2_kernel<<<M, 128, 0, stream>>>(P2, rs, cs, invdeg, b2, h2);

  // Heads (commuted): P3 = h2 @ [4 head mats]^T (fp32 out); out = mean_agg(P3_rel) + P3_root + bias
  gemm_kernel<<<1 * gy, 256, 0, stream>>>(
      h2, 512, Bt3, 512, nullptr, P3, 128, M, 128, 512, 0, 1, 1);
  float* outmu = (float*)d_out;
  float* outls = outmu + (size_t)M * 8;
  head_agg_kernel<<<(M * 16 + 255) / 256, 256, 0, stream>>>(
      P3, rs, cs, invdeg, bmu, bls, outmu, outls, M);
}